// Round 1
// baseline (294.573 us; speedup 1.0000x reference)
//
#include <hip/hip_runtime.h>

// Problem constants (fixed shapes)
#define BB 8192      // batch
#define DZ 1024
#define DS 64
#define DH 4096
#define KEXT (DH + DS)   // 4160: K of GEMM2 = [H | s]

typedef float floatx4 __attribute__((ext_vector_type(4)));
typedef __bf16 bf16x8 __attribute__((ext_vector_type(8)));
typedef __attribute__((address_space(1))) void* as1_void_ptr;
typedef __attribute__((address_space(3))) void* as3_void_ptr;

__device__ __forceinline__ void async_copy16(const void* g, void* l) {
    // global -> LDS direct copy, 16B per lane; LDS dest = wave-uniform base + lane*16
    __builtin_amdgcn_global_load_lds((as1_void_ptr)g, (as3_void_ptr)l, 16, 0, 0);
}

// ---------------- conversion kernels ----------------

__global__ void cvt_f32_bf16(const float* __restrict__ in, __bf16* __restrict__ out, int n4) {
    int i = blockIdx.x * blockDim.x + threadIdx.x;
    if (i < n4) {
        float4 v = ((const float4*)in)[i];
        __bf16* o = out + (size_t)i * 4;
        o[0] = (__bf16)v.x; o[1] = (__bf16)v.y; o[2] = (__bf16)v.z; o[3] = (__bf16)v.w;
    }
}

// B2b[j, 0:4096] = W2[j, :], B2b[j, 4096:4160] = C[j, :]   (j = 0..1023)
__global__ void build_B2(const float* __restrict__ W2, const float* __restrict__ C,
                         __bf16* __restrict__ B2b) {
    int j = blockIdx.x;
    for (int h = threadIdx.x; h < KEXT; h += 256) {
        float v = (h < DH) ? W2[(size_t)j * DH + h] : C[(size_t)j * DS + (h - DH)];
        B2b[(size_t)j * KEXT + h] = (__bf16)v;
    }
}

// Hb[b, 4096+k] = s[b, k]
__global__ void stage_s(const float* __restrict__ s, __bf16* __restrict__ Hb) {
    int idx = blockIdx.x * 256 + threadIdx.x;   // 0 .. 8192*64-1
    int b = idx >> 6, k = idx & 63;
    Hb[(size_t)b * KEXT + DH + k] = (__bf16)s[idx];
}

// ---------------- GEMM1: Hb[:, :4096] = relu(zb @ W1b^T + h1) ----------------
// NT layout: A = zb [8192 x 1024] (K-major), B = W1b [4096 x 1024] (K-major).
// 128x128 block tile, BK=32, 4 waves each computing 64x64 via 4x4 grid of 16x16x32 MFMA.

__global__ __launch_bounds__(256) void gemm1_relu(
    const __bf16* __restrict__ Ag, const __bf16* __restrict__ Bg,
    const float* __restrict__ h1, __bf16* __restrict__ Hb)
{
    constexpr int K = DZ, ldA = DZ, ldB = DZ;
    __shared__ __align__(16) __bf16 As[128 * 32];
    __shared__ __align__(16) __bf16 Bs[128 * 32];

    const int tid = threadIdx.x;
    const int wave = tid >> 6, lane = tid & 63;
    const int wm = wave >> 1, wn = wave & 1;
    const int row0 = blockIdx.x * 128;
    const int col0 = blockIdx.y * 128;

    // staging: thread t covers tile elements [q*2048 + t*8, +8), q = 0,1
    const __bf16* a0 = Ag + (size_t)(row0 + (tid >> 2)) * ldA + (tid & 3) * 8;
    const __bf16* b0 = Bg + (size_t)(col0 + (tid >> 2)) * ldB + (tid & 3) * 8;
    __bf16* lA = As + wave * 512;   // + lane*8 implicit
    __bf16* lB = Bs + wave * 512;

    // fragment read pointers (A layout: m = lane&15, k-chunk = lane>>4)
    const __bf16* Afrag = As + (wm * 64 + (lane & 15)) * 32 + (lane >> 4) * 8;
    const __bf16* Bfrag = Bs + (wn * 64 + (lane & 15)) * 32 + (lane >> 4) * 8;

    floatx4 acc[4][4];
#pragma unroll
    for (int i = 0; i < 4; ++i)
#pragma unroll
        for (int j = 0; j < 4; ++j) acc[i][j] = (floatx4)0.0f;

    for (int kt = 0; kt < K / 32; ++kt) {
        const __bf16* ak = a0 + kt * 32;
        const __bf16* bk = b0 + kt * 32;
        async_copy16(ak,            lA);
        async_copy16(ak + 64 * ldA, lA + 2048);
        async_copy16(bk,            lB);
        async_copy16(bk + 64 * ldB, lB + 2048);
        __builtin_amdgcn_s_waitcnt(0);
        __syncthreads();

        bf16x8 af[4], bfr[4];
#pragma unroll
        for (int i = 0; i < 4; ++i) af[i] = *(const bf16x8*)(Afrag + i * 16 * 32);
#pragma unroll
        for (int j = 0; j < 4; ++j) bfr[j] = *(const bf16x8*)(Bfrag + j * 16 * 32);
#pragma unroll
        for (int i = 0; i < 4; ++i)
#pragma unroll
            for (int j = 0; j < 4; ++j)
                acc[i][j] = __builtin_amdgcn_mfma_f32_16x16x32_bf16(af[i], bfr[j], acc[i][j], 0, 0, 0);
        __syncthreads();
    }

    // epilogue: C/D layout col = lane&15, row = (lane>>4)*4 + reg
    const int r0 = row0 + wm * 64 + (lane >> 4) * 4;
    const int c0 = col0 + wn * 64 + (lane & 15);
#pragma unroll
    for (int i = 0; i < 4; ++i) {
#pragma unroll
        for (int j = 0; j < 4; ++j) {
            int c = c0 + j * 16;
            float bias = h1[c];
#pragma unroll
            for (int rg = 0; rg < 4; ++rg) {
                int r = r0 + i * 16 + rg;
                float v = acc[i][j][rg] + bias;
                v = v > 0.0f ? v : 0.0f;
                Hb[(size_t)r * KEXT + c] = (__bf16)v;
            }
        }
    }
}

// ---------------- GEMM2: out = Hb @ B2b^T + A*z + h2 ----------------
// A = Hb [8192 x 4160] (K-major), B = B2b [1024 x 4160] (K-major), K = 4160.

__global__ __launch_bounds__(256) void gemm2_out(
    const __bf16* __restrict__ Ag, const __bf16* __restrict__ Bg,
    const float* __restrict__ Adiag, const float* __restrict__ h2,
    const float* __restrict__ zf, float* __restrict__ out)
{
    constexpr int K = KEXT, ldA = KEXT, ldB = KEXT;
    __shared__ __align__(16) __bf16 As[128 * 32];
    __shared__ __align__(16) __bf16 Bs[128 * 32];

    const int tid = threadIdx.x;
    const int wave = tid >> 6, lane = tid & 63;
    const int wm = wave >> 1, wn = wave & 1;
    const int row0 = blockIdx.x * 128;
    const int col0 = blockIdx.y * 128;

    const __bf16* a0 = Ag + (size_t)(row0 + (tid >> 2)) * ldA + (tid & 3) * 8;
    const __bf16* b0 = Bg + (size_t)(col0 + (tid >> 2)) * ldB + (tid & 3) * 8;
    __bf16* lA = As + wave * 512;
    __bf16* lB = Bs + wave * 512;

    const __bf16* Afrag = As + (wm * 64 + (lane & 15)) * 32 + (lane >> 4) * 8;
    const __bf16* Bfrag = Bs + (wn * 64 + (lane & 15)) * 32 + (lane >> 4) * 8;

    floatx4 acc[4][4];
#pragma unroll
    for (int i = 0; i < 4; ++i)
#pragma unroll
        for (int j = 0; j < 4; ++j) acc[i][j] = (floatx4)0.0f;

    for (int kt = 0; kt < K / 32; ++kt) {
        const __bf16* ak = a0 + kt * 32;
        const __bf16* bk = b0 + kt * 32;
        async_copy16(ak,            lA);
        async_copy16(ak + 64 * ldA, lA + 2048);
        async_copy16(bk,            lB);
        async_copy16(bk + 64 * ldB, lB + 2048);
        __builtin_amdgcn_s_waitcnt(0);
        __syncthreads();

        bf16x8 af[4], bfr[4];
#pragma unroll
        for (int i = 0; i < 4; ++i) af[i] = *(const bf16x8*)(Afrag + i * 16 * 32);
#pragma unroll
        for (int j = 0; j < 4; ++j) bfr[j] = *(const bf16x8*)(Bfrag + j * 16 * 32);
#pragma unroll
        for (int i = 0; i < 4; ++i)
#pragma unroll
            for (int j = 0; j < 4; ++j)
                acc[i][j] = __builtin_amdgcn_mfma_f32_16x16x32_bf16(af[i], bfr[j], acc[i][j], 0, 0, 0);
        __syncthreads();
    }

    const int r0 = row0 + wm * 64 + (lane >> 4) * 4;
    const int c0 = col0 + wn * 64 + (lane & 15);
#pragma unroll
    for (int i = 0; i < 4; ++i) {
#pragma unroll
        for (int j = 0; j < 4; ++j) {
            int c = c0 + j * 16;
            float aj = Adiag[c];
            float hj = h2[c];
#pragma unroll
            for (int rg = 0; rg < 4; ++rg) {
                int r = r0 + i * 16 + rg;
                out[(size_t)r * DZ + c] = acc[i][j][rg] + aj * zf[(size_t)r * DZ + c] + hj;
            }
        }
    }
}

// ---------------- launch ----------------

extern "C" void kernel_launch(void* const* d_in, const int* in_sizes, int n_in,
                              void* d_out, int out_size, void* d_ws, size_t ws_size,
                              hipStream_t stream) {
    const float* z  = (const float*)d_in[0];   // [8192,1024]
    const float* s  = (const float*)d_in[1];   // [8192,64]
    const float* A  = (const float*)d_in[2];   // [1024]
    const float* W1 = (const float*)d_in[3];   // [4096,1024]
    const float* W2 = (const float*)d_in[4];   // [1024,4096]
    const float* h1 = (const float*)d_in[5];   // [4096]
    const float* h2 = (const float*)d_in[6];   // [1024]
    const float* C  = (const float*)d_in[7];   // [1024,64]
    float* out = (float*)d_out;

    // workspace layout (bytes): Hb | zb | W1b | B2b  ~= 102 MB total
    char* ws = (char*)d_ws;
    size_t offHb  = 0;
    size_t offZb  = offHb  + (size_t)BB * KEXT * 2;      // 68,157,440
    size_t offW1b = offZb  + (size_t)BB * DZ * 2;        // +16,777,216
    size_t offB2b = offW1b + (size_t)DH * DZ * 2;        // +8,388,608
    __bf16* Hb  = (__bf16*)(ws + offHb);    // [8192 x 4160]: cols 0:4096 = relu(...), 4096:4160 = s
    __bf16* zb  = (__bf16*)(ws + offZb);    // [8192 x 1024]
    __bf16* W1b = (__bf16*)(ws + offW1b);   // [4096 x 1024]
    __bf16* B2b = (__bf16*)(ws + offB2b);   // [1024 x 4160] = [W2 | C]

    cvt_f32_bf16<<<(BB * DZ / 4 + 255) / 256, 256, 0, stream>>>(z, zb, BB * DZ / 4);
    cvt_f32_bf16<<<(DH * DZ / 4 + 255) / 256, 256, 0, stream>>>(W1, W1b, DH * DZ / 4);
    build_B2<<<DZ, 256, 0, stream>>>(W2, C, B2b);
    stage_s<<<BB * DS / 256, 256, 0, stream>>>(s, Hb);

    gemm1_relu<<<dim3(BB / 128, DH / 128), 256, 0, stream>>>(zb, W1b, h1, Hb);
    gemm2_out<<<dim3(BB / 128, DZ / 128), 256, 0, stream>>>(Hb, B2b, A, h2, z, out);
}